// Round 3
// baseline (65948.175 us; speedup 1.0000x reference)
//
#include <hip/hip_runtime.h>
#include <math.h>

#define D 512
#define H 512
#define NL 3
#define B 128
#define T 256
#define H5 2560
#define H6 3072

typedef __attribute__((ext_vector_type(8))) short short8;
typedef __attribute__((ext_vector_type(4))) float f32x4;

__device__ __forceinline__ ushort f2bf(float x) {
  unsigned u = __float_as_uint(x);
  return (ushort)((u + 0x7fffu + ((u >> 16) & 1u)) >> 16);
}
__device__ __forceinline__ float bf2f(ushort h) {
  return __uint_as_float(((unsigned)h) << 16);
}

// ---------------- W_hh transpose (fp32, for recurrent k_step): W[512][2560] -> WT[2560][512]
__global__ __launch_bounds__(256) void k_transpose(const float* __restrict__ W, float* __restrict__ WT) {
  __shared__ float tile[32][33];
  int tx = threadIdx.x & 31, ty = threadIdx.x >> 5; // 32 x 8
  int c0 = blockIdx.x * 32, r0 = blockIdx.y * 32;
#pragma unroll
  for (int i = 0; i < 4; ++i) {
    int r = r0 + ty + i * 8;
    tile[ty + i * 8][tx] = W[(size_t)r * H5 + c0 + tx];
  }
  __syncthreads();
#pragma unroll
  for (int i = 0; i < 4; ++i) {
    int c = c0 + ty + i * 8;
    WT[(size_t)c * D + r0 + tx] = tile[tx][ty + i * 8];
  }
}

// ---------------- W_ih transpose + split: W[512][3072] fp32 -> WThi/WTlo[3072][512] bf16
__global__ __launch_bounds__(256) void k_conv_w(const float* __restrict__ W,
                                                ushort* __restrict__ Whi, ushort* __restrict__ Wlo) {
  __shared__ float tile[32][33];
  int tx = threadIdx.x & 31, ty = threadIdx.x >> 5;
  int c0 = blockIdx.x * 32, r0 = blockIdx.y * 32;
#pragma unroll
  for (int i = 0; i < 4; ++i)
    tile[ty + i * 8][tx] = W[(size_t)(r0 + ty + i * 8) * H6 + c0 + tx];
  __syncthreads();
#pragma unroll
  for (int i = 0; i < 4; ++i) {
    int c = c0 + ty + i * 8;
    float v = tile[tx][ty + i * 8];
    ushort hi = f2bf(v);
    ushort lo = f2bf(v - bf2f(hi));
    Whi[(size_t)c * D + r0 + tx] = hi;
    Wlo[(size_t)c * D + r0 + tx] = lo;
  }
}

// ---------------- A gather + split: rows (t-local-major) -> Ahi/Alo[Mc][512] bf16
// amode 0: A = x [B,T,D]; amode 1: A = hid [T,B,H]; amode 2: hid, time-flipped per lens
__global__ __launch_bounds__(128) void k_conv_a(const float* __restrict__ A, int amode, int t0,
                                                const int* __restrict__ lens,
                                                ushort* __restrict__ Ahi, ushort* __restrict__ Alo) {
  int row = blockIdx.x; // tl*B + bb
  int tl = row >> 7, bb = row & 127;
  int pos = t0 + tl;
  const float* src;
  if (amode == 0) {
    src = A + ((size_t)bb * T + pos) * D;
  } else if (amode == 1) {
    src = A + ((size_t)pos * B + bb) * D;
  } else {
    int len = lens[bb];
    int sp = (pos < len) ? (len - 1 - pos) : pos;
    src = A + ((size_t)sp * B + bb) * D;
  }
  int c = threadIdx.x * 4;
  float4 v = *(const float4*)(src + c);
  ushort4 hi, lo;
  hi.x = f2bf(v.x); lo.x = f2bf(v.x - bf2f(hi.x));
  hi.y = f2bf(v.y); lo.y = f2bf(v.y - bf2f(hi.y));
  hi.z = f2bf(v.z); lo.z = f2bf(v.z - bf2f(hi.z));
  hi.w = f2bf(v.w); lo.w = f2bf(v.w - bf2f(hi.w));
  *(ushort4*)(Ahi + (size_t)row * D + c) = hi;
  *(ushort4*)(Alo + (size_t)row * D + c) = lo;
}

// ---------------- split-bf16 MFMA GEMM: C[Mc][3072] += A[Mc][512] * B[3072][512]^T
// A, B both K-contiguous bf16 (hi/lo pairs). 128x128 tile, BK=32, 4 waves (2x2),
// wave tile 64x64 = 4x4 fragments of mfma_f32_16x16x32_bf16, 3-term split product.
__global__ __launch_bounds__(256) void k_gemm_mfma(
    const ushort* __restrict__ Ahi, const ushort* __restrict__ Alo,
    const ushort* __restrict__ Bhi, const ushort* __restrict__ Blo,
    float* __restrict__ Cout) {
  // LDS: 4 tiles of [128 rows][32 bf16], row stride 80B (64B payload + 16B pad)
  __shared__ __align__(16) char lds[40960];
  const int tx = threadIdx.x;
  const int lane = tx & 63;
  const int wid = tx >> 6;
  const int wm = wid >> 1, wn = wid & 1;
  const int m0 = blockIdx.y * 128, n0 = blockIdx.x * 128;

  f32x4 acc[4][4];
#pragma unroll
  for (int f = 0; f < 4; ++f)
#pragma unroll
    for (int g = 0; g < 4; ++g) acc[f][g] = (f32x4){0.f, 0.f, 0.f, 0.f};

  for (int k0 = 0; k0 < D; k0 += 32) {
    uint4 rah[2], ral[2], rbh[2], rbl[2];
#pragma unroll
    for (int i = 0; i < 2; ++i) {
      int row = i * 64 + (tx >> 2);
      size_t goffA = (size_t)(m0 + row) * D + k0 + (size_t)(tx & 3) * 8;
      size_t goffB = (size_t)(n0 + row) * D + k0 + (size_t)(tx & 3) * 8;
      rah[i] = *(const uint4*)(Ahi + goffA);
      ral[i] = *(const uint4*)(Alo + goffA);
      rbh[i] = *(const uint4*)(Bhi + goffB);
      rbl[i] = *(const uint4*)(Blo + goffB);
    }
    __syncthreads(); // previous iter's fragment reads done before overwrite
#pragma unroll
    for (int i = 0; i < 2; ++i) {
      int row = i * 64 + (tx >> 2);
      int off = row * 80 + (tx & 3) * 16;
      *(uint4*)(lds + off) = rah[i];
      *(uint4*)(lds + 10240 + off) = ral[i];
      *(uint4*)(lds + 20480 + off) = rbh[i];
      *(uint4*)(lds + 30720 + off) = rbl[i];
    }
    __syncthreads();

    short8 ah[4], al[4], bh[4], bl[4];
#pragma unroll
    for (int f = 0; f < 4; ++f) {
      int off = (wm * 64 + f * 16 + (lane & 15)) * 80 + (lane >> 4) * 16;
      ah[f] = *(const short8*)(lds + off);
      al[f] = *(const short8*)(lds + 10240 + off);
    }
#pragma unroll
    for (int g = 0; g < 4; ++g) {
      int off = (wn * 64 + g * 16 + (lane & 15)) * 80 + (lane >> 4) * 16;
      bh[g] = *(const short8*)(lds + 20480 + off);
      bl[g] = *(const short8*)(lds + 30720 + off);
    }
#pragma unroll
    for (int f = 0; f < 4; ++f)
#pragma unroll
      for (int g = 0; g < 4; ++g) {
        acc[f][g] = __builtin_amdgcn_mfma_f32_16x16x32_bf16(ah[f], bh[g], acc[f][g], 0, 0, 0);
        acc[f][g] = __builtin_amdgcn_mfma_f32_16x16x32_bf16(ah[f], bl[g], acc[f][g], 0, 0, 0);
        acc[f][g] = __builtin_amdgcn_mfma_f32_16x16x32_bf16(al[f], bh[g], acc[f][g], 0, 0, 0);
      }
  }

  // D mapping (m89-verified): col = lane&15, row = (lane>>4)*4 + reg
  float* Cb = Cout + (size_t)(m0 + wm * 64 + (lane >> 4) * 4) * H6 + n0 + wn * 64 + (lane & 15);
#pragma unroll
  for (int f = 0; f < 4; ++f)
#pragma unroll
    for (int g = 0; g < 4; ++g)
#pragma unroll
      for (int r = 0; r < 4; ++r)
        Cb[(size_t)(f * 16 + r) * H6 + g * 16] = acc[f][g][r];
}

// ---------------- one recurrent step (split-K=2, 512 threads) ----------------
__global__ __launch_bounds__(512) void k_step(
    const float* __restrict__ tmpi, const float* __restrict__ whhT,
    const float* __restrict__ bvec, const float* __restrict__ dropl,
    const int* __restrict__ lens, const float* __restrict__ hd_in,
    float* __restrict__ hd_out, float* __restrict__ cbuf,
    float* __restrict__ hidl, float* __restrict__ outp,
    int t, int t0, int rev) {
  int tx = threadIdx.x;
  int ks = tx >> 8;
  int r = tx & 255;
  int jl = r & 3, bloc = r >> 2;
  int b = blockIdx.y * 64 + bloc;
  int j = blockIdx.x * 4 + jl;

  const float4* hp = (const float4*)(hd_in + (size_t)b * H) + ks * 64;
  const float4* w0 = (const float4*)(whhT + ((size_t)0 * H + j) * D) + ks * 64;
  const float4* w1 = (const float4*)(whhT + ((size_t)1 * H + j) * D) + ks * 64;
  const float4* w2 = (const float4*)(whhT + ((size_t)2 * H + j) * D) + ks * 64;
  const float4* w3 = (const float4*)(whhT + ((size_t)3 * H + j) * D) + ks * 64;
  const float4* w4 = (const float4*)(whhT + ((size_t)4 * H + j) * D) + ks * 64;

  float a0 = 0.f, a1 = 0.f, a2 = 0.f, a3 = 0.f, a4 = 0.f;
#pragma unroll 4
  for (int r4 = 0; r4 < 64; ++r4) {
    float4 h4 = hp[r4];
    float4 q;
    q = w0[r4]; a0 += h4.x * q.x + h4.y * q.y + h4.z * q.z + h4.w * q.w;
    q = w1[r4]; a1 += h4.x * q.x + h4.y * q.y + h4.z * q.z + h4.w * q.w;
    q = w2[r4]; a2 += h4.x * q.x + h4.y * q.y + h4.z * q.z + h4.w * q.w;
    q = w3[r4]; a3 += h4.x * q.x + h4.y * q.y + h4.z * q.z + h4.w * q.w;
    q = w4[r4]; a4 += h4.x * q.x + h4.y * q.y + h4.z * q.z + h4.w * q.w;
  }

  __shared__ float red[5][256];
  if (ks) {
    red[0][r] = a0; red[1][r] = a1; red[2][r] = a2; red[3][r] = a3; red[4][r] = a4;
  }
  __syncthreads();
  if (!ks) {
    a0 += red[0][r]; a1 += red[1][r]; a2 += red[2][r]; a3 += red[3][r]; a4 += red[4][r];

    int len = lens[b];
    bool valid = t < len;
    const float* ti = tmpi + ((size_t)(t - t0) * B + b) * H6;
    float gi = a0 + ti[0 * H + j] + bvec[0 * H + j];
    float gf = a1 + ti[1 * H + j] + bvec[1 * H + j];
    float gg = a2 + ti[2 * H + j] + bvec[2 * H + j];
    float go = a3 + ti[3 * H + j] + bvec[3 * H + j];
    float gr = a4 + ti[4 * H + j] + bvec[4 * H + j];
    float lin = ti[5 * H + j];

    float si = 1.f / (1.f + expf(-gi));
    float sf = 1.f / (1.f + expf(-gf));
    float tg = tanhf(gg);
    float so = 1.f / (1.f + expf(-go));
    float sr = 1.f / (1.f + expf(-gr));

    float cold = cbuf[(size_t)b * H + j];
    float cn = sf * cold + si * tg;
    float hn = sr * (so * tanhf(cn)) + (1.f - sr) * lin;
    float hout = valid ? hn : 0.f;
    cbuf[(size_t)b * H + j] = valid ? cn : cold;
    hd_out[(size_t)b * H + j] = hout * dropl[(size_t)b * H + j];
    int ts = rev ? (valid ? (len - 1 - t) : t) : t;
    hidl[((size_t)ts * B + b) * H + j] = hout;
    if (outp) outp[((size_t)b * T + ts) * H + j] = hout;
  }
}

extern "C" void kernel_launch(void* const* d_in, const int* in_sizes, int n_in,
                              void* d_out, int out_size, void* d_ws, size_t ws_size,
                              hipStream_t stream) {
  const float* x = (const float*)d_in[0];
  const int* lens = (const int*)d_in[1];
  const float* weight = (const float*)d_in[2];
  const float* bias = (const float*)d_in[3];
  const float* drop = (const float*)d_in[4];
  float* out = (float*)d_out;
  const size_t HS = (size_t)T * B * H;
  float* hid[3] = {out + HS, out + 2 * HS, out + 3 * HS};

  float* ws = (float*)d_ws;
  int Tc = 64;
  auto need = [&](int tc) -> size_t {
    size_t f = ((size_t)tc * B * H6 + (size_t)H5 * D + 3 * (size_t)B * H) * 4;
    size_t bb = ((size_t)2 * tc * B * D + (size_t)2 * H6 * D) * 2;
    return f + bb;
  };
  while (Tc > 1 && need(Tc) > ws_size) Tc >>= 1;

  float* tmpi = ws;
  float* whhT = tmpi + (size_t)Tc * B * H6;
  float* hdA = whhT + (size_t)H5 * D;
  float* hdB = hdA + (size_t)B * H;
  float* cbuf = hdB + (size_t)B * H;
  ushort* Ahi = (ushort*)(cbuf + (size_t)B * H);
  ushort* Alo = Ahi + (size_t)Tc * B * D;
  ushort* WThi = Alo + (size_t)Tc * B * D;
  ushort* WTlo = WThi + (size_t)H6 * D;

  const size_t wih_off[3] = {0, 2883584, 5767168};
  const size_t whh_off[3] = {1572864, 4456448, 7340032};

  for (int l = 0; l < NL; ++l) {
    const float* wih = weight + wih_off[l];
    const float* whh = weight + whh_off[l];
    const float* bv = bias + (size_t)l * H5;
    const float* dl = drop + (size_t)l * B * H;

    hipLaunchKernelGGL(k_transpose, dim3(80, 16), dim3(256), 0, stream, whh, whhT);
    hipLaunchKernelGGL(k_conv_w, dim3(96, 16), dim3(256), 0, stream, wih, WThi, WTlo);

    const float* A;
    int amode;
    if (l == 0) {
      A = x; amode = 0;
    } else if (l == 1) {
      A = hid[0]; amode = 2; // read layer-0 output time-flipped
    } else {
      A = hid[1]; amode = 1;
    }

    hipMemsetAsync(hdA, 0, (size_t)B * H * 4, stream);
    hipMemsetAsync(cbuf, 0, (size_t)B * H * 4, stream);

    int rev = (l == 1) ? 1 : 0;
    float* op = (l == 2) ? out : nullptr;

    for (int t0 = 0; t0 < T; t0 += Tc) {
      hipLaunchKernelGGL(k_conv_a, dim3(Tc * B), dim3(128), 0, stream, A, amode, t0, lens, Ahi, Alo);
      hipLaunchKernelGGL(k_gemm_mfma, dim3(24, Tc), dim3(256), 0, stream, Ahi, Alo, WThi, WTlo, tmpi);
      for (int t = t0; t < t0 + Tc; ++t) {
        float* hin = (t & 1) ? hdB : hdA;
        float* hout = (t & 1) ? hdA : hdB;
        hipLaunchKernelGGL(k_step, dim3(128, 2), dim3(512), 0, stream,
                           tmpi, whhT, bv, dl, lens, hin, hout, cbuf, hid[l], op, t, t0, rev);
      }
    }
  }
}

// Round 6
// 36013.504 us; speedup vs baseline: 1.8312x; 1.8312x over previous
//
#include <hip/hip_runtime.h>
#include <hip/hip_cooperative_groups.h>
#include <math.h>

namespace cg = cooperative_groups;

#define D 512
#define H 512
#define NL 3
#define B 128
#define T 256
#define H5 2560
#define H6 3072

typedef __attribute__((ext_vector_type(8))) short short8;
typedef __attribute__((ext_vector_type(4))) float f32x4;
typedef __attribute__((ext_vector_type(8))) unsigned short ushort8_t;

__device__ __forceinline__ ushort f2bf(float x) {
  unsigned u = __float_as_uint(x);
  return (ushort)((u + 0x7fffu + ((u >> 16) & 1u)) >> 16);
}
__device__ __forceinline__ float bf2f(ushort h) { return __uint_as_float(((unsigned)h) << 16); }
__device__ __forceinline__ float sigf(float x) { return 1.f / (1.f + expf(-x)); }

// ---------------- W_ih transpose + split: W[512][3072] fp32 -> WThi/WTlo[3072][512] bf16
__global__ __launch_bounds__(256) void k_conv_w(const float* __restrict__ W,
                                                ushort* __restrict__ Whi, ushort* __restrict__ Wlo) {
  __shared__ float tile[32][33];
  int tx = threadIdx.x & 31, ty = threadIdx.x >> 5;
  int c0 = blockIdx.x * 32, r0 = blockIdx.y * 32;
#pragma unroll
  for (int i = 0; i < 4; ++i)
    tile[ty + i * 8][tx] = W[(size_t)(r0 + ty + i * 8) * H6 + c0 + tx];
  __syncthreads();
#pragma unroll
  for (int i = 0; i < 4; ++i) {
    int c = c0 + ty + i * 8;
    float v = tile[tx][ty + i * 8];
    ushort hi = f2bf(v);
    ushort lo = f2bf(v - bf2f(hi));
    Whi[(size_t)c * D + r0 + tx] = hi;
    Wlo[(size_t)c * D + r0 + tx] = lo;
  }
}

// ---------------- W_hh -> per-block MFMA fragment image (bf16 hi/lo) ----------------
// img[nb][ks][nt][{hi,lo}][lane][8] ; nb=0..31 (j-slab of 16), ks=0..15 (K=32 slab), nt=0..4 (gate)
// B-fragment layout for mfma_f32_16x16x32_bf16: n = lane&15, k = (lane>>4)*8 + i
__global__ __launch_bounds__(256) void k_prep_whh(const float* __restrict__ W, char* __restrict__ img) {
  int tid = blockIdx.x * 256 + threadIdx.x; // 163840 total
  int lane = tid & 63;
  int r = tid >> 6;
  int nt = r % 5; r /= 5;
  int ks = r & 15;
  int nb = r >> 4;
  int col = nt * 512 + nb * 16 + (lane & 15);
  int kb = ks * 32 + ((lane >> 4) << 3);
  ushort8_t hi, lo;
#pragma unroll
  for (int i = 0; i < 8; ++i) {
    float w = W[(size_t)(kb + i) * H5 + col];
    ushort uh = f2bf(w);
    hi[i] = uh;
    lo[i] = f2bf(w - bf2f(uh));
  }
  char* dst = img + (size_t)nb * 163840 + ((size_t)(ks * 5 + nt) * 2) * 1024 + lane * 16;
  *(uint4*)dst = *(uint4*)&hi;
  *(uint4*)(dst + 1024) = *(uint4*)&lo;
}

// ---------------- A gather + split for ih-GEMM (bf16) ----------------
__global__ __launch_bounds__(128) void k_conv_a(const float* __restrict__ A, int amode, int t0,
                                                const int* __restrict__ lens,
                                                ushort* __restrict__ Ahi, ushort* __restrict__ Alo) {
  int row = blockIdx.x; // tl*B + bb
  int tl = row >> 7, bb = row & 127;
  int pos = t0 + tl;
  const float* src;
  if (amode == 0) {
    src = A + ((size_t)bb * T + pos) * D;
  } else if (amode == 1) {
    src = A + ((size_t)pos * B + bb) * D;
  } else {
    int len = lens[bb];
    int sp = (pos < len) ? (len - 1 - pos) : pos;
    src = A + ((size_t)sp * B + bb) * D;
  }
  int c = threadIdx.x * 4;
  float4 v = *(const float4*)(src + c);
  ushort4 hi, lo;
  hi.x = f2bf(v.x); lo.x = f2bf(v.x - bf2f(hi.x));
  hi.y = f2bf(v.y); lo.y = f2bf(v.y - bf2f(hi.y));
  hi.z = f2bf(v.z); lo.z = f2bf(v.z - bf2f(hi.z));
  hi.w = f2bf(v.w); lo.w = f2bf(v.w - bf2f(hi.w));
  *(ushort4*)(Ahi + (size_t)row * D + c) = hi;
  *(ushort4*)(Alo + (size_t)row * D + c) = lo;
}

// ---------------- split-bf16 MFMA GEMM (validated round 3) ----------------
__global__ __launch_bounds__(256) void k_gemm_mfma(
    const ushort* __restrict__ Ahi, const ushort* __restrict__ Alo,
    const ushort* __restrict__ Bhi, const ushort* __restrict__ Blo,
    float* __restrict__ Cout) {
  __shared__ __align__(16) char lds[40960];
  const int tx = threadIdx.x;
  const int lane = tx & 63;
  const int wid = tx >> 6;
  const int wm = wid >> 1, wn = wid & 1;
  const int m0 = blockIdx.y * 128, n0 = blockIdx.x * 128;

  f32x4 acc[4][4];
#pragma unroll
  for (int f = 0; f < 4; ++f)
#pragma unroll
    for (int g = 0; g < 4; ++g) acc[f][g] = (f32x4){0.f, 0.f, 0.f, 0.f};

  for (int k0 = 0; k0 < D; k0 += 32) {
    uint4 rah[2], ral[2], rbh[2], rbl[2];
#pragma unroll
    for (int i = 0; i < 2; ++i) {
      int row = i * 64 + (tx >> 2);
      size_t goffA = (size_t)(m0 + row) * D + k0 + (size_t)(tx & 3) * 8;
      size_t goffB = (size_t)(n0 + row) * D + k0 + (size_t)(tx & 3) * 8;
      rah[i] = *(const uint4*)(Ahi + goffA);
      ral[i] = *(const uint4*)(Alo + goffA);
      rbh[i] = *(const uint4*)(Bhi + goffB);
      rbl[i] = *(const uint4*)(Blo + goffB);
    }
    __syncthreads();
#pragma unroll
    for (int i = 0; i < 2; ++i) {
      int row = i * 64 + (tx >> 2);
      int off = row * 80 + (tx & 3) * 16;
      *(uint4*)(lds + off) = rah[i];
      *(uint4*)(lds + 10240 + off) = ral[i];
      *(uint4*)(lds + 20480 + off) = rbh[i];
      *(uint4*)(lds + 30720 + off) = rbl[i];
    }
    __syncthreads();

    short8 ah[4], al[4], bh[4], bl[4];
#pragma unroll
    for (int f = 0; f < 4; ++f) {
      int off = (wm * 64 + f * 16 + (lane & 15)) * 80 + (lane >> 4) * 16;
      ah[f] = *(const short8*)(lds + off);
      al[f] = *(const short8*)(lds + 10240 + off);
    }
#pragma unroll
    for (int g = 0; g < 4; ++g) {
      int off = (wn * 64 + g * 16 + (lane & 15)) * 80 + (lane >> 4) * 16;
      bh[g] = *(const short8*)(lds + 20480 + off);
      bl[g] = *(const short8*)(lds + 30720 + off);
    }
#pragma unroll
    for (int f = 0; f < 4; ++f)
#pragma unroll
      for (int g = 0; g < 4; ++g) {
        acc[f][g] = __builtin_amdgcn_mfma_f32_16x16x32_bf16(ah[f], bh[g], acc[f][g], 0, 0, 0);
        acc[f][g] = __builtin_amdgcn_mfma_f32_16x16x32_bf16(ah[f], bl[g], acc[f][g], 0, 0, 0);
        acc[f][g] = __builtin_amdgcn_mfma_f32_16x16x32_bf16(al[f], bh[g], acc[f][g], 0, 0, 0);
      }
  }
  float* Cb = Cout + (size_t)(m0 + wm * 64 + (lane >> 4) * 4) * H6 + n0 + wn * 64 + (lane & 15);
#pragma unroll
  for (int f = 0; f < 4; ++f)
#pragma unroll
    for (int g = 0; g < 4; ++g)
#pragma unroll
      for (int r = 0; r < 4; ++r)
        Cb[(size_t)(f * 16 + r) * H6 + g * 16] = acc[f][g][r];
}

// ---------------- persistent cooperative recurrence ----------------
// 32 blocks x 256 thr. Block nb owns j-slab [nb*16, nb*16+16) x 5 gates.
// 4 waves: (mh = wid>>1: M half) x (ng = wid&1: gate tiles {0,1,2} / {3,4}).
// W fragments (bf16 hi/lo) streamed from per-block image via 2x20KB LDS double buffer.
// h' (h*drop, bf16 hi/lo fragment-blocked) exchanged via global, double-buffered by parity.
template <int NT>
__device__ __forceinline__ void mfma_tiles(const char* wbuf, int ksl, int ntb, int lane,
                                           const char* hcur, int mh, int ks, f32x4 acc[4][3]) {
  short8 ah[4], al[4];
#pragma unroll
  for (int m = 0; m < 4; ++m) {
    const char* hb = hcur + (size_t)(((mh * 4 + m) * 16 + ks) * 2) * 1024 + lane * 16;
    ah[m] = *(const short8*)hb;
    al[m] = *(const short8*)(hb + 1024);
  }
#pragma unroll
  for (int n = 0; n < NT; ++n) {
    const char* wb = wbuf + ((ksl * 5 + ntb + n) * 2) * 1024 + lane * 16;
    short8 bh = *(const short8*)wb;
    short8 bl = *(const short8*)(wb + 1024);
#pragma unroll
    for (int m = 0; m < 4; ++m) {
      acc[m][n] = __builtin_amdgcn_mfma_f32_16x16x32_bf16(ah[m], bh, acc[m][n], 0, 0, 0);
      acc[m][n] = __builtin_amdgcn_mfma_f32_16x16x32_bf16(al[m], bh, acc[m][n], 0, 0, 0);
      acc[m][n] = __builtin_amdgcn_mfma_f32_16x16x32_bf16(ah[m], bl, acc[m][n], 0, 0, 0);
      acc[m][n] = __builtin_amdgcn_mfma_f32_16x16x32_bf16(al[m], bl, acc[m][n], 0, 0, 0);
    }
  }
}

__global__ __launch_bounds__(256) void k_recur(
    const float* __restrict__ tmpi, const char* __restrict__ wimg,
    const float* __restrict__ bias, const float* __restrict__ dropl,
    const int* __restrict__ lens, char* __restrict__ hpar,
    float* __restrict__ cbuf, float* __restrict__ hidl, float* __restrict__ outp,
    int t0, int nsteps, int rev) {
  __shared__ __align__(16) char ldsW[40960]; // W dbuf (2x20KB); reused as 5x[128][16] fp32 ep planes
  __shared__ float biasLds[80];
  cg::grid_group grid = cg::this_grid();

  const int nb = blockIdx.x;
  const int j0 = nb * 16;
  const int tx = threadIdx.x;
  const int lane = tx & 63;
  const int wid = tx >> 6;
  const int mh = wid >> 1, ng = wid & 1;
  const char* wimg_b = wimg + (size_t)nb * 163840;

  if (tx < 80) biasLds[tx] = bias[(tx >> 4) * 512 + j0 + (tx & 15)];

  // epilogue thread mapping: b = tx>>1, jh = tx&1 (8 consecutive j's each)
  const int eb = tx >> 1, ejh = tx & 1;
  const int elen = lens[eb];
  float c8[8], dr8[8];
  {
    const float* cb = cbuf + (size_t)eb * H + j0 + ejh * 8;
    float4 v0 = *(const float4*)cb, v1 = *(const float4*)(cb + 4);
    c8[0] = v0.x; c8[1] = v0.y; c8[2] = v0.z; c8[3] = v0.w;
    c8[4] = v1.x; c8[5] = v1.y; c8[6] = v1.z; c8[7] = v1.w;
    const float* db = dropl + (size_t)eb * H + j0 + ejh * 8;
    float4 d0 = *(const float4*)db, d1 = *(const float4*)(db + 4);
    dr8[0] = d0.x; dr8[1] = d0.y; dr8[2] = d0.z; dr8[3] = d0.w;
    dr8[4] = d1.x; dr8[5] = d1.y; dr8[6] = d1.z; dr8[7] = d1.w;
  }
  __syncthreads();

  for (int s = 0; s < nsteps; ++s) {
    const int t = t0 + s;
    const char* hcur = hpar + (size_t)(t & 1) * 262144;
    char* hnxt = hpar + (size_t)((t + 1) & 1) * 262144;

    f32x4 acc[4][3];
#pragma unroll
    for (int m = 0; m < 4; ++m)
#pragma unroll
      for (int n = 0; n < 3; ++n) acc[m][n] = (f32x4){0.f, 0.f, 0.f, 0.f};

    // stage W chunk 0
    {
      const uint4* srcv = (const uint4*)wimg_b;
      uint4* dstv = (uint4*)ldsW;
      for (int i = tx; i < 1280; i += 256) dstv[i] = srcv[i];
    }
    __syncthreads();
    for (int cc = 0; cc < 8; ++cc) {
      if (cc < 7) {
        const uint4* srcv = (const uint4*)(wimg_b + (size_t)(cc + 1) * 20480);
        uint4* dstv = (uint4*)(ldsW + ((cc + 1) & 1) * 20480);
        for (int i = tx; i < 1280; i += 256) dstv[i] = srcv[i];
      }
      const char* wbuf = ldsW + (cc & 1) * 20480;
#pragma unroll
      for (int ksl = 0; ksl < 2; ++ksl) {
        int ks = cc * 2 + ksl;
        if (ng == 0) mfma_tiles<3>(wbuf, ksl, 0, lane, hcur, mh, ks, acc);
        else         mfma_tiles<2>(wbuf, ksl, 3, lane, hcur, mh, ks, acc);
      }
      __syncthreads();
    }
    // acc -> ep planes in LDS: ep[g][b][j16] fp32 (5 planes x 8KB = 40960B exact)
    {
      float* ep = (float*)ldsW;
      const int NTn = ng ? 2 : 3;
      const int ntb = ng * 3;
      for (int n = 0; n < NTn; ++n)
#pragma unroll
        for (int m = 0; m < 4; ++m)
#pragma unroll
          for (int r = 0; r < 4; ++r) {
            int b = (mh * 4 + m) * 16 + (lane >> 4) * 4 + r;
            ep[(ntb + n) * 2048 + b * 16 + (lane & 15)] = acc[m][n][r];
          }
    }
    __syncthreads();
    // epilogue: each thread finishes 8 outputs (b=eb, j = j0+ejh*8 .. +8)
    {
      const float* ep = (const float*)ldsW;
      bool valid = t < elen;
      const float* tib = tmpi + ((size_t)s * B + eb) * H6 + j0 + ejh * 8;
      float4 tv[6][2];
#pragma unroll
      for (int g = 0; g < 6; ++g) {
        tv[g][0] = *(const float4*)(tib + (size_t)g * 512);
        tv[g][1] = *(const float4*)(tib + (size_t)g * 512 + 4);
      }
      int ts = rev ? (valid ? (elen - 1 - t) : t) : t;
      float4 ho[2];
      ushort8_t uhi, ulo;
#pragma unroll
      for (int jj = 0; jj < 8; ++jj) {
        int ji = ejh * 8 + jj;
        float gi = ep[0 * 2048 + eb * 16 + ji] + ((const float*)&tv[0][jj >> 2])[jj & 3] + biasLds[0 * 16 + ji];
        float gf = ep[1 * 2048 + eb * 16 + ji] + ((const float*)&tv[1][jj >> 2])[jj & 3] + biasLds[1 * 16 + ji];
        float gg = ep[2 * 2048 + eb * 16 + ji] + ((const float*)&tv[2][jj >> 2])[jj & 3] + biasLds[2 * 16 + ji];
        float go = ep[3 * 2048 + eb * 16 + ji] + ((const float*)&tv[3][jj >> 2])[jj & 3] + biasLds[3 * 16 + ji];
        float gr = ep[4 * 2048 + eb * 16 + ji] + ((const float*)&tv[4][jj >> 2])[jj & 3] + biasLds[4 * 16 + ji];
        float lin = ((const float*)&tv[5][jj >> 2])[jj & 3];
        float si = sigf(gi), sf = sigf(gf), so = sigf(go), sr = sigf(gr);
        float tg = tanhf(gg);
        float cn = sf * c8[jj] + si * tg;
        float hn = sr * (so * tanhf(cn)) + (1.f - sr) * lin;
        float hout = valid ? hn : 0.f;
        c8[jj] = valid ? cn : c8[jj];
        ((float*)ho)[jj] = hout;
        float hd = hout * dr8[jj];
        ushort uh = f2bf(hd);
        uhi[jj] = uh;
        ulo[jj] = f2bf(hd - bf2f(uh));
      }
      float* hb = hidl + ((size_t)ts * B + eb) * H + j0 + ejh * 8;
      *(float4*)hb = ho[0];
      *(float4*)(hb + 4) = ho[1];
      if (outp) {
        float* ob = outp + ((size_t)eb * T + ts) * H + j0 + ejh * 8;
        *(float4*)ob = ho[0];
        *(float4*)(ob + 4) = ho[1];
      }
      // write h' fragments for next step: A-frag layout row=lane&15, k=(lane>>4)*8+i
      int j = j0 + ejh * 8; // 8-aligned
      int mt = eb >> 4, ks2 = j >> 5, lp = (eb & 15) + ((j >> 3) & 3) * 16;
      char* hfb = hnxt + (size_t)((mt * 16 + ks2) * 2) * 1024 + lp * 16;
      *(uint4*)hfb = *(uint4*)&uhi;
      *(uint4*)(hfb + 1024) = *(uint4*)&ulo;
    }
    __threadfence();
    grid.sync();
  }
  // save c state for next chunk
  {
    float* cb = cbuf + (size_t)eb * H + j0 + ejh * 8;
    *(float4*)cb = make_float4(c8[0], c8[1], c8[2], c8[3]);
    *(float4*)(cb + 4) = make_float4(c8[4], c8[5], c8[6], c8[7]);
  }
}

extern "C" void kernel_launch(void* const* d_in, const int* in_sizes, int n_in,
                              void* d_out, int out_size, void* d_ws, size_t ws_size,
                              hipStream_t stream) {
  const float* x = (const float*)d_in[0];
  const int* lens = (const int*)d_in[1];
  const float* weight = (const float*)d_in[2];
  const float* bias = (const float*)d_in[3];
  const float* drop = (const float*)d_in[4];
  float* out = (float*)d_out;
  const size_t HS = (size_t)T * B * H;
  float* hid[3] = {out + HS, out + 2 * HS, out + 3 * HS};

  int Tc = 64;
  auto need = [&](int tc) -> size_t {
    size_t f = (size_t)tc * B * H6 * 4;                            // tmpi
    size_t bb = ((size_t)2 * tc * B * D + (size_t)2 * H6 * D) * 2; // Ahi/Alo + WThi/WTlo
    return f + bb + 5242880 + 524288 + 262144 + 4096;
  };
  while (Tc > 1 && need(Tc) > ws_size) Tc >>= 1;

  char* p = (char*)d_ws;
  float* tmpi = (float*)p; p += (size_t)Tc * B * H6 * 4;
  ushort* Ahi = (ushort*)p; p += (size_t)Tc * B * D * 2;
  ushort* Alo = (ushort*)p; p += (size_t)Tc * B * D * 2;
  ushort* WThi = (ushort*)p; p += (size_t)H6 * D * 2;
  ushort* WTlo = (ushort*)p; p += (size_t)H6 * D * 2;
  char* wimg = p; p += 5242880;
  char* hpar = p; p += 524288;
  float* cbuf = (float*)p; p += 262144;

  const size_t wih_off[3] = {0, 2883584, 5767168};
  const size_t whh_off[3] = {1572864, 4456448, 7340032};

  for (int l = 0; l < NL; ++l) {
    const float* wih = weight + wih_off[l];
    const float* whh = weight + whh_off[l];
    const float* bv = bias + (size_t)l * H5;
    const float* dl = drop + (size_t)l * B * H;

    hipLaunchKernelGGL(k_conv_w, dim3(96, 16), dim3(256), 0, stream, wih, WThi, WTlo);
    hipLaunchKernelGGL(k_prep_whh, dim3(640), dim3(256), 0, stream, whh, wimg);
    hipMemsetAsync(hpar, 0, 262144, stream); // parity-0 h' fragments (h0 = 0)
    hipMemsetAsync(cbuf, 0, 262144, stream); // c0 = 0

    const float* A;
    int amode;
    if (l == 0) { A = x; amode = 0; }
    else if (l == 1) { A = hid[0]; amode = 2; }
    else { A = hid[1]; amode = 1; }

    int rev = (l == 1) ? 1 : 0;
    float* op = (l == 2) ? out : nullptr;

    for (int t0 = 0; t0 < T; t0 += Tc) {
      hipLaunchKernelGGL(k_conv_a, dim3(Tc * B), dim3(128), 0, stream, A, amode, t0, lens, Ahi, Alo);
      hipLaunchKernelGGL(k_gemm_mfma, dim3(24, Tc), dim3(256), 0, stream, Ahi, Alo, WThi, WTlo, tmpi);
      {
        const float* a0 = tmpi; const char* a1 = wimg; const float* a2 = bv; const float* a3 = dl;
        const int* a4 = lens; char* a5 = hpar; float* a6 = cbuf; float* a7 = hid[l]; float* a8 = op;
        int a9 = t0, a10 = Tc, a11 = rev;
        void* args[] = {&a0, &a1, &a2, &a3, &a4, &a5, &a6, &a7, &a8, &a9, &a10, &a11};
        hipLaunchCooperativeKernel((const void*)k_recur, dim3(32), dim3(256), args, 0, stream);
      }
    }
  }
}